// Round 7
// baseline (179.093 us; speedup 1.0000x reference)
//
#include <hip/hip_runtime.h>
#include <math.h>

#define BATCH 32768
#define NCLS  1000
#define NVEC  250            // 1000 / 4 float4s per row
#define SCALE 30.0f
#define K_LOG2E 43.28085122666891f   // 30 * log2(e)
#define LN2 0.69314718055994531f
#define RPW 4                         // rows per wave
#define NBLOCKS (BATCH / (4 * RPW))   // 2048 blocks: 4 waves x 4 rows

typedef float f4 __attribute__((ext_vector_type(4)));

__device__ __forceinline__ void load_row_nt(const f4* __restrict__ rowv, int lane,
                                            f4 w[4]) {
    w[0] = __builtin_nontemporal_load(rowv + lane);
    w[1] = __builtin_nontemporal_load(rowv + lane + 64);
    w[2] = __builtin_nontemporal_load(rowv + lane + 128);
    if (lane < NVEC - 192)
        w[3] = __builtin_nontemporal_load(rowv + lane + 192);
    else
        w[3] = (f4){-INFINITY, -INFINITY, -INFINITY, -INFINITY};
}

// Margin-apply: subtract mt at the target component; owner lane records score.
__device__ __forceinline__ void apply_margin(const f4 w[4], int lane, int t, float mt,
                                             float s[16], float* st) {
    #pragma unroll
    for (int j = 0; j < 4; ++j) {
        f4 v = w[j];
        const int base = 4 * (lane + 64 * j);
        if (base + 0 == t) { v.x -= mt; *st = v.x; }
        if (base + 1 == t) { v.y -= mt; *st = v.y; }
        if (base + 2 == t) { v.z -= mt; *st = v.z; }
        if (base + 3 == t) { v.w -= mt; *st = v.w; }
        s[4*j+0] = v.x; s[4*j+1] = v.y; s[4*j+2] = v.z; s[4*j+3] = v.w;
    }
}

// Two interleaved row reductions -> nll0 + nll1.
__device__ __forceinline__ float reduce2(const float s0[16], const float s1[16],
                                         float st0, float st1, int t0, int t1) {
    st0 = __shfl(st0, (t0 >> 2) & 63);   // owner lane is wave-uniform
    st1 = __shfl(st1, (t1 >> 2) & 63);

    float m0 = s0[0], m1 = s1[0];
    #pragma unroll
    for (int k = 1; k < 16; ++k) { m0 = fmaxf(m0, s0[k]); m1 = fmaxf(m1, s1[k]); }
    #pragma unroll
    for (int off = 1; off < 64; off <<= 1) {
        m0 = fmaxf(m0, __shfl_xor(m0, off));
        m1 = fmaxf(m1, __shfl_xor(m1, off));
    }

    float l0 = 0.0f, l1 = 0.0f;
    #pragma unroll
    for (int k = 0; k < 16; ++k) {
        l0 += __builtin_amdgcn_exp2f(K_LOG2E * (s0[k] - m0));
        l1 += __builtin_amdgcn_exp2f(K_LOG2E * (s1[k] - m1));
    }
    #pragma unroll
    for (int off = 1; off < 64; off <<= 1) {
        l0 += __shfl_xor(l0, off);
        l1 += __shfl_xor(l1, off);
    }
    return SCALE * ((m0 - st0) + (m1 - st1))
         + LN2 * (__builtin_amdgcn_logf(l0) + __builtin_amdgcn_logf(l1));
}

__global__ __launch_bounds__(256) void ldam_kernel(
    const float* __restrict__ logits,
    const float* __restrict__ margins,
    const int*   __restrict__ targets,
    float*       __restrict__ partials)
{
    const int wave = threadIdx.x >> 6;              // 0..3
    const int lane = threadIdx.x & 63;
    const int row0 = (blockIdx.x * 4 + wave) * RPW; // 4 rows per wave

    const int4  tv = *(const int4*)(targets + row0);
    const float mt0 = margins[tv.x], mt1 = margins[tv.y];
    const float mt2 = margins[tv.z], mt3 = margins[tv.w];

    const f4* rv = (const f4*)(logits + (size_t)row0 * NCLS);

    // Burst rows 0,1.
    f4 a[4], b[4];
    load_row_nt(rv, lane, a);
    load_row_nt(rv + NVEC, lane, b);

    // Consume a,b into s-arrays (waits vmcnt on first 8 loads only).
    float s0[16], s1[16], st0 = 0.0f, st1 = 0.0f;
    apply_margin(a, lane, tv.x, mt0, s0, &st0);
    apply_margin(b, lane, tv.y, mt1, s1, &st1);

    // Burst rows 2,3 — in flight across rows 0,1's reduce chains.
    f4 c[4], d[4];
    load_row_nt(rv + 2 * NVEC, lane, c);
    load_row_nt(rv + 3 * NVEC, lane, d);

    float acc = reduce2(s0, s1, st0, st1, tv.x, tv.y);

    float s2[16], s3[16], st2 = 0.0f, st3 = 0.0f;
    apply_margin(c, lane, tv.z, mt2, s2, &st2);
    apply_margin(d, lane, tv.w, mt3, s3, &st3);
    acc += reduce2(s2, s3, st2, st3, tv.z, tv.w);

    __shared__ float partial[4];
    if (lane == 0) partial[wave] = acc;
    __syncthreads();
    if (threadIdx.x == 0)
        partials[blockIdx.x] = partial[0] + partial[1] + partial[2] + partial[3];
}

// Single-block reduction of NBLOCKS partials -> mean in out[0].
__global__ __launch_bounds__(256) void ldam_reduce_kernel(
    const float* __restrict__ partials,
    float*       __restrict__ out)
{
    const int tid  = threadIdx.x;
    const int lane = tid & 63;
    const int wave = tid >> 6;

    // 2048 floats = 512 float4s; 256 threads * 2 float4 each.
    const float4* pv = (const float4*)partials;
    float sum = 0.0f;
    #pragma unroll
    for (int j = 0; j < 2; ++j) {
        const float4 v = pv[tid + 256 * j];
        sum += (v.x + v.y) + (v.z + v.w);
    }

    #pragma unroll
    for (int off = 1; off < 64; off <<= 1)
        sum += __shfl_xor(sum, off);

    __shared__ float ws_[4];
    if (lane == 0) ws_[wave] = sum;
    __syncthreads();
    if (tid == 0)
        out[0] = (ws_[0] + ws_[1] + ws_[2] + ws_[3]) * (1.0f / (float)BATCH);
}

extern "C" void kernel_launch(void* const* d_in, const int* in_sizes, int n_in,
                              void* d_out, int out_size, void* d_ws, size_t ws_size,
                              hipStream_t stream) {
    const float* logits  = (const float*)d_in[0];
    const float* margins = (const float*)d_in[1];
    const int*   targets = (const int*)d_in[2];
    float* out      = (float*)d_out;
    float* partials = (float*)d_ws;

    ldam_kernel<<<NBLOCKS, 256, 0, stream>>>(logits, margins, targets, partials);
    ldam_reduce_kernel<<<1, 256, 0, stream>>>(partials, out);
}

// Round 8
// 178.218 us; speedup vs baseline: 1.0049x; 1.0049x over previous
//
#include <hip/hip_runtime.h>
#include <math.h>

#define BATCH 32768
#define NCLS  1000
#define NVEC  250            // 1000 / 4 float4s per row
#define SCALE 30.0f
#define K_LOG2E 43.28085122666891f   // 30 * log2(e)
#define LN2 0.69314718055994531f
#define NBLOCKS (BATCH / 8)  // 4096 blocks: 4 waves x 2 rows per wave

typedef float f4 __attribute__((ext_vector_type(4)));

__device__ __forceinline__ void load_row_nt(const f4* __restrict__ rowv, int lane,
                                            f4 w[4]) {
    w[0] = __builtin_nontemporal_load(rowv + lane);
    w[1] = __builtin_nontemporal_load(rowv + lane + 64);
    w[2] = __builtin_nontemporal_load(rowv + lane + 128);
    if (lane < NVEC - 192)
        w[3] = __builtin_nontemporal_load(rowv + lane + 192);
    else
        w[3] = (f4){-INFINITY, -INFINITY, -INFINITY, -INFINITY};
}

__global__ __launch_bounds__(256) void ldam_kernel(
    const float* __restrict__ logits,
    const float* __restrict__ margins,
    const int*   __restrict__ targets,
    float*       __restrict__ partials)
{
    const int wave = threadIdx.x >> 6;        // 0..3
    const int lane = threadIdx.x & 63;
    const int row0 = (blockIdx.x * 4 + wave) * 2;  // 2 rows per wave

    const int2  tv = *(const int2*)(targets + row0);
    const int   t0 = tv.x, t1 = tv.y;
    const float mt0 = margins[t0], mt1 = margins[t1];

    const f4* rv0 = (const f4*)(logits + (size_t)row0 * NCLS);
    const f4* rv1 = rv0 + NVEC;

    // 8 nt loads in flight before any use.
    f4 a[4], b[4];
    load_row_nt(rv0, lane, a);
    load_row_nt(rv1, lane, b);

    // Apply margin at target component; owner lane keeps the target score.
    float s0[16], s1[16];
    float st0 = 0.0f, st1 = 0.0f;
    #pragma unroll
    for (int j = 0; j < 4; ++j) {
        f4 v = a[j];
        const int base = 4 * (lane + 64 * j);
        if (base + 0 == t0) { v.x -= mt0; st0 = v.x; }
        if (base + 1 == t0) { v.y -= mt0; st0 = v.y; }
        if (base + 2 == t0) { v.z -= mt0; st0 = v.z; }
        if (base + 3 == t0) { v.w -= mt0; st0 = v.w; }
        s0[4*j+0] = v.x; s0[4*j+1] = v.y; s0[4*j+2] = v.z; s0[4*j+3] = v.w;
    }
    #pragma unroll
    for (int j = 0; j < 4; ++j) {
        f4 v = b[j];
        const int base = 4 * (lane + 64 * j);
        if (base + 0 == t1) { v.x -= mt1; st1 = v.x; }
        if (base + 1 == t1) { v.y -= mt1; st1 = v.y; }
        if (base + 2 == t1) { v.z -= mt1; st1 = v.z; }
        if (base + 3 == t1) { v.w -= mt1; st1 = v.w; }
        s1[4*j+0] = v.x; s1[4*j+1] = v.y; s1[4*j+2] = v.z; s1[4*j+3] = v.w;
    }

    // Owner lane of the target's float4 is wave-uniform: one shfl broadcast
    // replaces a 6-step max butterfly.
    st0 = __shfl(st0, (t0 >> 2) & 63);
    st1 = __shfl(st1, (t1 >> 2) & 63);

    // Two independent max chains, interleaved for ILP.
    float m0 = s0[0], m1 = s1[0];
    #pragma unroll
    for (int k = 1; k < 16; ++k) { m0 = fmaxf(m0, s0[k]); m1 = fmaxf(m1, s1[k]); }
    #pragma unroll
    for (int off = 1; off < 64; off <<= 1) {
        m0 = fmaxf(m0, __shfl_xor(m0, off));
        m1 = fmaxf(m1, __shfl_xor(m1, off));
    }

    // exp sums (padding lanes contribute exp2(-inf) = 0), interleaved.
    float l0 = 0.0f, l1 = 0.0f;
    #pragma unroll
    for (int k = 0; k < 16; ++k) {
        l0 += __builtin_amdgcn_exp2f(K_LOG2E * (s0[k] - m0));
        l1 += __builtin_amdgcn_exp2f(K_LOG2E * (s1[k] - m1));
    }
    #pragma unroll
    for (int off = 1; off < 64; off <<= 1) {
        l0 += __shfl_xor(l0, off);
        l1 += __shfl_xor(l1, off);
    }

    const float nll = SCALE * ((m0 - st0) + (m1 - st1))
                    + LN2 * (__builtin_amdgcn_logf(l0) + __builtin_amdgcn_logf(l1));

    __shared__ float partial[4];
    if (lane == 0) partial[wave] = nll;
    __syncthreads();
    if (threadIdx.x == 0)
        partials[blockIdx.x] = partial[0] + partial[1] + partial[2] + partial[3];
}

// Single-block reduction of NBLOCKS partials -> mean in out[0].
__global__ __launch_bounds__(256) void ldam_reduce_kernel(
    const float* __restrict__ partials,
    float*       __restrict__ out)
{
    const int tid  = threadIdx.x;
    const int lane = tid & 63;
    const int wave = tid >> 6;

    // 4096 floats = 1024 float4s; 256 threads * 4 float4 each.
    const float4* pv = (const float4*)partials;
    float sum = 0.0f;
    #pragma unroll
    for (int j = 0; j < 4; ++j) {
        const float4 v = pv[tid + 256 * j];
        sum += (v.x + v.y) + (v.z + v.w);
    }

    #pragma unroll
    for (int off = 1; off < 64; off <<= 1)
        sum += __shfl_xor(sum, off);

    __shared__ float ws_[4];
    if (lane == 0) ws_[wave] = sum;
    __syncthreads();
    if (tid == 0)
        out[0] = (ws_[0] + ws_[1] + ws_[2] + ws_[3]) * (1.0f / (float)BATCH);
}

extern "C" void kernel_launch(void* const* d_in, const int* in_sizes, int n_in,
                              void* d_out, int out_size, void* d_ws, size_t ws_size,
                              hipStream_t stream) {
    const float* logits  = (const float*)d_in[0];
    const float* margins = (const float*)d_in[1];
    const int*   targets = (const int*)d_in[2];
    float* out      = (float*)d_out;
    float* partials = (float*)d_ws;

    ldam_kernel<<<NBLOCKS, 256, 0, stream>>>(logits, margins, targets, partials);
    ldam_reduce_kernel<<<1, 256, 0, stream>>>(partials, out);
}